// Round 2
// baseline (1424.274 us; speedup 1.0000x reference)
//
#include <hip/hip_runtime.h>
#include <cstdint>
#include <cstddef>

// Problem constants
constexpr int CB  = 4;
constexpr int CT  = 2048;
constexpr int CD  = 1024;
constexpr int CE  = 4096;
constexpr int CM  = CB * CT;      // 8192 token rows
constexpr int CN2E = 2 * CE;      // 8192
constexpr int NCHUNK = 32;        // per-batch T chunks for scan
constexpr int CLEN = CT / NCHUNK; // 64

typedef float  f32x4  __attribute__((ext_vector_type(4)));
typedef __bf16 bf16x8 __attribute__((ext_vector_type(8)));

__device__ __forceinline__ unsigned short f2bf(float f) {
  unsigned int u = __float_as_uint(f);
  unsigned int r = u + 0x7FFFu + ((u >> 16) & 1u);   // RNE
  return (unsigned short)(r >> 16);
}
__device__ __forceinline__ float bf2f(unsigned short h) {
  return __uint_as_float(((unsigned int)h) << 16);
}

// ---------------- fp32 -> bf16 pack (vectorized x4) ----------------
__global__ __launch_bounds__(256) void k_f2bf4(const float* __restrict__ in,
                                               unsigned short* __restrict__ out, int n4) {
  int i = blockIdx.x * 256 + threadIdx.x;
  if (i >= n4) return;
  float4 v = ((const float4*)in)[i];
  ushort4 o;
  o.x = f2bf(v.x); o.y = f2bf(v.y); o.z = f2bf(v.z); o.w = f2bf(v.w);
  ((ushort4*)out)[i] = o;
}

// ---------------- async global->LDS, 16B per lane ----------------
__device__ __forceinline__ void gll16(const unsigned short* g, void* l) {
  __builtin_amdgcn_global_load_lds(
      (const __attribute__((address_space(1))) void*)g,
      (__attribute__((address_space(3))) void*)l, 16, 0, 0);
}

// ---------------- GEMM: C[m][n] = sum_k A[m][k]*Bw[n][k] + epilogue ----------
// 128x128 tile, BK=32, 4 waves (each a 64x64 quadrant of 4x4 16x16 frags).
// EPI 0: bias (bias0|bias1 split at esplit) + silu -> bf16, out0|out1 (ld0 each)
// EPI 1: bias0 + identity -> fp32 out0
// EPI 2: bias0; col<esplit -> sigmoid(-v); else g(v) -> bf16 out0 (ld0 = N)
template <int EPI>
__global__ __launch_bounds__(256) void gemm_bt(
    const unsigned short* __restrict__ A,   // [M][lda] bf16
    const unsigned short* __restrict__ Bw,  // [N][K]   bf16 (tight)
    const float* __restrict__ bias0,
    const float* __restrict__ bias1,
    void* __restrict__ out0,
    void* __restrict__ out1,
    int M, int N, int K, int lda, int ld0, int esplit) {
  __shared__ __align__(16) unsigned short As[128 * 32];
  __shared__ __align__(16) unsigned short Bs[128 * 32];

  const int nbn = N >> 7;
  const int nbm = M >> 7;
  const int nwg = nbm * nbn;
  int bid = blockIdx.x;
  bid = (bid & 7) * (nwg >> 3) + (bid >> 3);   // XCD-aware swizzle (nwg % 8 == 0)
  const int bm = bid / nbn;
  const int bn = bid - bm * nbn;

  const int tid  = threadIdx.x;
  const int lane = tid & 63;
  const int wv   = tid >> 6;
  const int wr   = wv >> 1;
  const int wc   = wv & 1;
  const int lrow = lane & 15;
  const int lk   = lane >> 4;

  const unsigned short* Abase = A  + (size_t)bm * 128 * lda;
  const unsigned short* Bbase = Bw + (size_t)bn * 128 * K;

  const int r0 = tid >> 2;         // 0..63 (row within half-tile)
  const int c0 = (tid & 3) * 8;    // k-element offset of 16B chunk

  char* AsB = (char*)As + (size_t)wv * 1024;   // wave-uniform LDS dest base
  char* BsB = (char*)Bs + (size_t)wv * 1024;

  f32x4 zero = {0.f, 0.f, 0.f, 0.f};
  f32x4 acc[4][4];
#pragma unroll
  for (int m = 0; m < 4; m++)
#pragma unroll
    for (int n = 0; n < 4; n++) acc[m][n] = zero;

  for (int kt = 0; kt < K; kt += 32) {
    __syncthreads();
    gll16(Abase + (size_t)r0 * lda + kt + c0,        AsB);
    gll16(Abase + (size_t)(r0 + 64) * lda + kt + c0, AsB + 4096);
    gll16(Bbase + (size_t)r0 * K + kt + c0,          BsB);
    gll16(Bbase + (size_t)(r0 + 64) * K + kt + c0,   BsB + 4096);
    __syncthreads();   // compiler drains vmcnt(0) before barrier

    const bf16x8* Av = (const bf16x8*)As;
    const bf16x8* Bv = (const bf16x8*)Bs;
    bf16x8 af[4], bfv[4];
#pragma unroll
    for (int m = 0; m < 4; m++) af[m]  = Av[(wr * 64 + m * 16 + lrow) * 4 + lk];
#pragma unroll
    for (int n = 0; n < 4; n++) bfv[n] = Bv[(wc * 64 + n * 16 + lrow) * 4 + lk];
#pragma unroll
    for (int m = 0; m < 4; m++)
#pragma unroll
      for (int n = 0; n < 4; n++)
        acc[m][n] = __builtin_amdgcn_mfma_f32_16x16x32_bf16(af[m], bfv[n], acc[m][n], 0, 0, 0);
  }

  // C/D layout: col = lane&15, row = (lane>>4)*4 + reg
  const int rbase = bm * 128 + wr * 64 + (lane >> 4) * 4;
  const int cbase = bn * 128 + wc * 64 + (lane & 15);
#pragma unroll
  for (int n = 0; n < 4; n++) {
    const int col = cbase + n * 16;
    float bi;
    if (EPI == 0) bi = (col < esplit) ? bias0[col] : bias1[col - esplit];
    else          bi = bias0[col];
#pragma unroll
    for (int m = 0; m < 4; m++) {
#pragma unroll
      for (int r = 0; r < 4; r++) {
        const int row = rbase + m * 16 + r;
        float v = acc[m][n][r] + bi;
        if (EPI == 0) {
          float sg = 1.f / (1.f + __expf(-v));
          unsigned short o = f2bf(v * sg);
          if (col < esplit) ((unsigned short*)out0)[(size_t)row * ld0 + col] = o;
          else              ((unsigned short*)out1)[(size_t)row * ld0 + (col - esplit)] = o;
        } else if (EPI == 1) {
          ((float*)out0)[(size_t)row * ld0 + col] = v;
        } else {  // EPI == 2: gate transform
          unsigned short o;
          if (col < esplit) {
            // coeff = sigmoid(-v), overflow-stable
            float e = __expf(-fabsf(v));
            float inv = 1.f / (1.f + e);
            o = f2bf((v >= 0.f) ? e * inv : inv);
          } else {
            // gf = g(v): v+0.5 for v>=0 else sigmoid(v)
            float gf;
            if (v >= 0.f) gf = v + 0.5f;
            else { float eh = __expf(v); gf = eh / (1.f + eh); }
            o = f2bf(gf);
          }
          ((unsigned short*)out0)[(size_t)row * ld0 + col] = o;
        }
      }
    }
  }
}

// ---------------- scan pass1 (per batch): A = prod c, B = local recurrence ---
// ghc: [CT][2E] bf16 — coeff cols [0,E), gf cols [E,2E). value = (1-c)*gf.
// grid 512: eg = bid&63 (E/64 groups), cq = bid>>6 (8); block 64 lanes x 4 waves
__global__ __launch_bounds__(256) void k_scan1(const unsigned short* __restrict__ ghc,
                                               float* __restrict__ Ac,
                                               float* __restrict__ Bc) {
  int tid = threadIdx.x;
  int lane = tid & 63, cw = tid >> 6;
  int bid = blockIdx.x;
  int eg = bid & 63;
  int cq = bid >> 6;
  int chunk = cq * 4 + cw;        // 0..31
  int e = eg * 64 + lane;
  const unsigned short* cp = ghc + (size_t)(chunk * CLEN) * CN2E + e;
  float h = 0.f, A = 1.f;
#pragma unroll 8
  for (int t = 0; t < CLEN; t++) {
    float c  = bf2f(cp[(size_t)t * CN2E]);
    float gf = bf2f(cp[(size_t)t * CN2E + CE]);
    float v  = (1.f - c) * gf;
    h = __builtin_fmaf(c, h, v);
    A *= c;
  }
  Ac[(size_t)chunk * CE + e] = A;
  Bc[(size_t)chunk * CE + e] = h;
}

// ---------------- scan pass2 (per batch): combine -> exclusive h_start -------
__global__ __launch_bounds__(256) void k_scan2(const float* __restrict__ Ac,
                                               const float* __restrict__ Bc,
                                               float* __restrict__ Hs) {
  int e = blockIdx.x * 256 + threadIdx.x;   // CE total
  float h = 0.f;
#pragma unroll
  for (int ch = 0; ch < NCHUNK; ch++) {
    Hs[(size_t)ch * CE + e] = h;
    h = __builtin_fmaf(Ac[(size_t)ch * CE + e], h, Bc[(size_t)ch * CE + e]);
  }
}

// ---------------- scan pass3 (per batch): recompute, s = x_skip + h (bf16) ----
__global__ __launch_bounds__(256) void k_scan3(const unsigned short* __restrict__ ghc,
                                               const float* __restrict__ Hs,
                                               const unsigned short* __restrict__ xs,
                                               unsigned short* __restrict__ sp) {
  int tid = threadIdx.x;
  int lane = tid & 63, cw = tid >> 6;
  int bid = blockIdx.x;
  int eg = bid & 63;
  int cq = bid >> 6;
  int chunk = cq * 4 + cw;
  int e = eg * 64 + lane;
  float h = Hs[(size_t)chunk * CE + e];
  const unsigned short* cp  = ghc + (size_t)(chunk * CLEN) * CN2E + e;
  const unsigned short* xsp = xs  + (size_t)(chunk * CLEN) * CE + e;
  unsigned short*       spp = sp  + (size_t)(chunk * CLEN) * CE + e;
#pragma unroll 4
  for (int t = 0; t < CLEN; t++) {
    float c  = bf2f(cp[(size_t)t * CN2E]);
    float gf = bf2f(cp[(size_t)t * CN2E + CE]);
    float v  = (1.f - c) * gf;
    h = __builtin_fmaf(c, h, v);
    float s = h + bf2f(xsp[(size_t)t * CE]);
    spp[(size_t)t * CE] = f2bf(s);
  }
}

// =======================================================================
extern "C" void kernel_launch(void* const* d_in, const int* in_sizes, int n_in,
                              void* d_out, int out_size, void* d_ws, size_t ws_size,
                              hipStream_t stream) {
  const float* x  = (const float*)d_in[0];
  const float* W1 = (const float*)d_in[1];
  const float* b1 = (const float*)d_in[2];
  const float* W2 = (const float*)d_in[3];
  const float* b2 = (const float*)d_in[4];
  const float* Wg = (const float*)d_in[5];
  const float* bg = (const float*)d_in[6];
  const float* Wo = (const float*)d_in[7];
  const float* bo = (const float*)d_in[8];
  float* out = (float*)d_out;

  // ---- workspace layout (peak 233.5 MB, aggressively aliased) ----
  const size_t MB = 1024 * 1024;
  const size_t REQUIRED = 234 * MB;
  if (ws_size < REQUIRED) {
    // Diagnostic: not enough scratch — fail cleanly (absmax) instead of faulting.
    return;
  }
  char* ws = (char*)d_ws;
  unsigned short* wgb   = (unsigned short*)(ws);             // 64 MB  Wg bf16 [2E][E]
  unsigned short* wob   = (unsigned short*)(ws + 64 * MB);   //  8 MB  Wo bf16 [D][E]
  unsigned short* wcat  = (unsigned short*)(ws + 72 * MB);   // 16 MB  [W1;W2] bf16 (dead after GEMM A)
  unsigned short* xb    = (unsigned short*)(ws + 88 * MB);   // 16 MB  x bf16    (dead after GEMM A)
  unsigned short* ghc   = (unsigned short*)(ws + 72 * MB);   // 32 MB  per-batch coeff|gf (aliases wcat+xb)
  unsigned short* xin   = (unsigned short*)(ws + 104 * MB);  // 64 MB  x_in bf16 [M][E]; becomes sbuf
  unsigned short* xskip = (unsigned short*)(ws + 168 * MB);  // 64 MB  x_skip bf16 [M][E]
  float* Ac = (float*)(ws + 232 * MB);                       // 0.5 MB
  float* Bc = (float*)(ws + 232 * MB + 512 * 1024);          // 0.5 MB
  float* Hs = (float*)(ws + 233 * MB);                       // 0.5 MB

  // ---- pack fp32 -> bf16 ----
  {
    int n4;
    n4 = CM * CD / 4;   k_f2bf4<<<n4 / 256, 256, 0, stream>>>(x,  xb,   n4);
    n4 = CE * CD / 4;   k_f2bf4<<<n4 / 256, 256, 0, stream>>>(W1, wcat, n4);
    n4 = CE * CD / 4;   k_f2bf4<<<n4 / 256, 256, 0, stream>>>(W2, wcat + (size_t)CE * CD, n4);
    n4 = CN2E * CE / 4; k_f2bf4<<<n4 / 256, 256, 0, stream>>>(Wg, wgb,  n4);
    n4 = CD * CE / 4;   k_f2bf4<<<n4 / 256, 256, 0, stream>>>(Wo, wob,  n4);
  }

  // ---- GEMM A: [x_in|x_skip] = silu(xb @ wcat^T + [b1|b2]); M=8192 N=8192 K=1024
  gemm_bt<0><<<(CM / 128) * (CN2E / 128), 256, 0, stream>>>(
      xb, wcat, b1, b2, xin, xskip, CM, CN2E, CD, CD, CE, CE);

  // ---- per batch: gate GEMM (+transform epilogue) then chunked scan ----
  for (int b = 0; b < CB; b++) {
    const unsigned short* xin_b = xin + (size_t)b * CT * CE;
    gemm_bt<2><<<(CT / 128) * (CN2E / 128), 256, 0, stream>>>(
        xin_b, wgb, bg, nullptr, ghc, nullptr, CT, CN2E, CE, CE, CN2E, CE);
    k_scan1<<<512, 256, 0, stream>>>(ghc, Ac, Bc);
    k_scan2<<<CE / 256, 256, 0, stream>>>(Ac, Bc, Hs);
    // sbuf rows of batch b overwrite xin rows of batch b (already consumed)
    k_scan3<<<512, 256, 0, stream>>>(ghc, Hs, xskip + (size_t)b * CT * CE,
                                     xin + (size_t)b * CT * CE);
  }

  // ---- GEMM C: out = sbuf @ Wo^T + bo; M=8192 N=1024 K=4096 ----
  gemm_bt<1><<<(CM / 128) * (CD / 128), 256, 0, stream>>>(
      xin, wob, bo, nullptr, out, nullptr, CM, CD, CE, CE, CD, 0);
}

// Round 3
// 978.911 us; speedup vs baseline: 1.4550x; 1.4550x over previous
//
#include <hip/hip_runtime.h>
#include <cstdint>
#include <cstddef>

// Problem constants
constexpr int CB  = 4;
constexpr int CT  = 2048;
constexpr int CD  = 1024;
constexpr int CE  = 4096;
constexpr int CM  = CB * CT;      // 8192 token rows
constexpr int CN2E = 2 * CE;      // 8192
constexpr int NCHUNK = 32;        // per-batch T chunks for scan
constexpr int CLEN = CT / NCHUNK; // 64

typedef float  f32x4  __attribute__((ext_vector_type(4)));
typedef __bf16 bf16x8 __attribute__((ext_vector_type(8)));

__device__ __forceinline__ unsigned short f2bf(float f) {
  unsigned int u = __float_as_uint(f);
  unsigned int r = u + 0x7FFFu + ((u >> 16) & 1u);   // RNE
  return (unsigned short)(r >> 16);
}
__device__ __forceinline__ float bf2f(unsigned short h) {
  return __uint_as_float(((unsigned int)h) << 16);
}

// ---------------- fp32 -> bf16 pack (vectorized x4) ----------------
__global__ __launch_bounds__(256) void k_f2bf4(const float* __restrict__ in,
                                               unsigned short* __restrict__ out, int n4) {
  int i = blockIdx.x * 256 + threadIdx.x;
  if (i >= n4) return;
  float4 v = ((const float4*)in)[i];
  ushort4 o;
  o.x = f2bf(v.x); o.y = f2bf(v.y); o.z = f2bf(v.z); o.w = f2bf(v.w);
  ((ushort4*)out)[i] = o;
}

// ---------------- async global->LDS, 16B per lane ----------------
__device__ __forceinline__ void gll16(const unsigned short* g, void* l) {
  __builtin_amdgcn_global_load_lds(
      (const __attribute__((address_space(1))) void*)g,
      (__attribute__((address_space(3))) void*)l, 16, 0, 0);
}

// =====================================================================
// 256x256 tile, BK=32, 8 waves (2M x 4N), 4-deep LDS buffer rotation,
// counted vmcnt (T4), XOR-swizzled LDS (T2), setprio around MFMA (T5).
// LDS: 4 bufs x (A[256][32] 16KB | B[256][32] 16KB) = 128 KB dynamic.
// Buffer rotation safety: tile t computes buf[t&3]; stage of tile t+3
// writes buf[(t+3)&3], whose last reader was tile t-1 — its reads
// completed (lgkmcnt before MFMA) before the barrier at top of tile t,
// which precedes the stage issue. No write-under-read by construction.
// EPI 0: bias(b0|b1 @esplit) + silu -> bf16 out0|out1 (ld0 each)
// EPI 2: bias0; col<esplit -> sigmoid(-v) else g(v) -> bf16 out0
template <int EPI>
__global__ __launch_bounds__(512, 2) void gemm256(
    const unsigned short* __restrict__ A,   // [M][lda] bf16
    const unsigned short* __restrict__ Bw,  // [N][K]   bf16 (tight)
    const float* __restrict__ bias0,
    const float* __restrict__ bias1,
    void* __restrict__ out0,
    void* __restrict__ out1,
    int M, int N, int K, int lda, int ld0, int esplit) {
  extern __shared__ char lds[];   // 131072 bytes

  const int nbn = N >> 8;
  const int nbm = M >> 8;
  const int nwg = nbm * nbn;
  int bid = blockIdx.x;
  int tau = (bid & 7) * (nwg >> 3) + (bid >> 3);   // XCD chunking (nwg%8==0)
  const int gsz = nbm * 4;                          // group = 4 bn-cols x all bm
  int gg  = tau / gsz;
  int rem = tau - gg * gsz;
  const int bm = rem >> 2;
  const int bn = gg * 4 + (rem & 3);

  const int tid  = threadIdx.x;
  const int lane = tid & 63;
  const int wv   = tid >> 6;
  const int wr   = wv >> 2;       // 0..1
  const int wc   = wv & 3;        // 0..3

  // ---- staging: source-side swizzle permutation (LDS dest stays linear) ----
  // linear LDS byte for thread t is t*16; swz flips bits 4-5 by bits 7-8:
  // t' = t ^ ((t>>3)&3)
  const int tp   = tid ^ ((tid >> 3) & 3);
  const int srow = tp >> 2;         // 0..127
  const int scol = (tp & 3) * 8;    // k-element offset of 16B chunk

  const unsigned short* Abase = A  + (size_t)bm * 256 * lda;
  const unsigned short* Bbase = Bw + (size_t)bn * 256 * (size_t)K;
  const int ldsw = wv * 1024;       // wave-uniform lane-linear staging base
  const int NT = K >> 5;

  auto stageA = [&](int t) {
    char* base = lds + (size_t)(t & 3) * 32768 + ldsw;
    const int kt = t * 32;
    gll16(Abase + (size_t)srow * lda + kt + scol,         base);
    gll16(Abase + (size_t)(srow + 128) * lda + kt + scol, base + 8192);
  };
  auto stageB = [&](int t) {
    char* base = lds + (size_t)(t & 3) * 32768 + 16384 + ldsw;
    const int kt = t * 32;
    gll16(Bbase + (size_t)srow * K + kt + scol,           base);
    gll16(Bbase + (size_t)(srow + 128) * K + kt + scol,   base + 8192);
  };

  // ---- fragment read offsets (within buffer), swizzled ----
  // logical byte = row*64 + g*16; swz: g ^= (row>>1)&3  (row bits 1-2 fixed
  // under mf*16 steps, so per-lane base is frag-independent)
  const int lr = lane & 15, gq = lane >> 4;
  const int arow = wr * 128 + lr;
  const int aoff = arow * 64 + (gq ^ ((arow >> 1) & 3)) * 16;
  const int brow = wc * 64 + lr;
  const int boff = 16384 + brow * 64 + (gq ^ ((brow >> 1) & 3)) * 16;

  f32x4 acc[8][4];
#pragma unroll
  for (int m = 0; m < 8; m++)
#pragma unroll
    for (int n = 0; n < 4; n++) acc[m][n] = (f32x4){0.f, 0.f, 0.f, 0.f};

  // ---- prologue: stage tiles 0,1,2 (12 glls/wave) ----
  stageA(0); stageB(0); stageA(1); stageB(1); stageA(2); stageB(2);

  for (int t = 0; t < NT; t++) {
    // counted vmcnt: allow 8 newest (tiles t+1,t+2) in flight -> tile t landed
    if (t < NT - 2)       asm volatile("s_waitcnt vmcnt(8)" ::: "memory");
    else if (t == NT - 2) asm volatile("s_waitcnt vmcnt(4)" ::: "memory");
    else                  asm volatile("s_waitcnt vmcnt(0)" ::: "memory");
    __builtin_amdgcn_sched_barrier(0);
    __builtin_amdgcn_s_barrier();          // all waves' tile-t data in LDS
    __builtin_amdgcn_sched_barrier(0);

    const char* bufp = lds + (size_t)(t & 3) * 32768;
    bf16x8 af[4], bfr[4];
    // ---- phase A: ds_read 8 (A mf0-3, B nf0-3) + stage A-halves of t+3 ----
#pragma unroll
    for (int i = 0; i < 4; i++) af[i]  = *(const bf16x8*)(bufp + aoff + i * 1024);
#pragma unroll
    for (int i = 0; i < 4; i++) bfr[i] = *(const bf16x8*)(bufp + boff + i * 1024);
    if (t + 3 < NT) stageA(t + 3);
    __builtin_amdgcn_sched_barrier(0);
    __builtin_amdgcn_s_barrier();
    __builtin_amdgcn_sched_barrier(0);
    __builtin_amdgcn_s_setprio(1);
#pragma unroll
    for (int m = 0; m < 4; m++)
#pragma unroll
      for (int n = 0; n < 4; n++)
        acc[m][n] = __builtin_amdgcn_mfma_f32_16x16x32_bf16(af[m], bfr[n], acc[m][n], 0, 0, 0);
    __builtin_amdgcn_s_setprio(0);
    __builtin_amdgcn_sched_barrier(0);
    __builtin_amdgcn_s_barrier();
    __builtin_amdgcn_sched_barrier(0);
    // ---- phase B: ds_read 4 (A mf4-7; B reused) + stage B-halves of t+3 ----
#pragma unroll
    for (int i = 0; i < 4; i++) af[i] = *(const bf16x8*)(bufp + aoff + (i + 4) * 1024);
    if (t + 3 < NT) stageB(t + 3);
    __builtin_amdgcn_sched_barrier(0);
    __builtin_amdgcn_s_barrier();
    __builtin_amdgcn_sched_barrier(0);
    __builtin_amdgcn_s_setprio(1);
#pragma unroll
    for (int m = 0; m < 4; m++)
#pragma unroll
      for (int n = 0; n < 4; n++)
        acc[m + 4][n] = __builtin_amdgcn_mfma_f32_16x16x32_bf16(af[m], bfr[n], acc[m + 4][n], 0, 0, 0);
    __builtin_amdgcn_s_setprio(0);
    // next iteration's vmcnt+barrier closes the phase
  }

  // ---- epilogue: C/D layout col=lane&15, row=(lane>>4)*4+reg ----
  const int rb = bm * 256 + wr * 128 + (lane >> 4) * 4;
  const int cb = bn * 256 + wc * 64 + (lane & 15);
#pragma unroll
  for (int nf = 0; nf < 4; nf++) {
    const int col = cb + nf * 16;
    float bi;
    if (EPI == 0) bi = (col < esplit) ? bias0[col] : bias1[col - esplit];
    else          bi = bias0[col];
#pragma unroll
    for (int mf = 0; mf < 8; mf++) {
#pragma unroll
      for (int r = 0; r < 4; r++) {
        const int row = rb + mf * 16 + r;
        float v = acc[mf][nf][r] + bi;
        if (EPI == 0) {
          float sg = 1.f / (1.f + __expf(-v));
          unsigned short o = f2bf(v * sg);
          if (col < esplit) ((unsigned short*)out0)[(size_t)row * ld0 + col] = o;
          else              ((unsigned short*)out1)[(size_t)row * ld0 + (col - esplit)] = o;
        } else {  // EPI == 2: gate transform
          unsigned short o;
          if (col < esplit) {
            float e = __expf(-fabsf(v));
            float inv = 1.f / (1.f + e);
            o = f2bf((v >= 0.f) ? e * inv : inv);     // sigmoid(-v)
          } else {
            float gf;
            if (v >= 0.f) gf = v + 0.5f;
            else { float eh = __expf(v); gf = eh / (1.f + eh); }
            o = f2bf(gf);                              // g(v)
          }
          ((unsigned short*)out0)[(size_t)row * ld0 + col] = o;
        }
      }
    }
  }
}

// ---------------- 128^2 m97-structure GEMM (kept for GEMM C) ----------------
__global__ __launch_bounds__(256) void gemm_bt1(
    const unsigned short* __restrict__ A,   // [M][lda] bf16
    const unsigned short* __restrict__ Bw,  // [N][K]   bf16 (tight)
    const float* __restrict__ bias0,
    float* __restrict__ out0,
    int M, int N, int K, int lda, int ld0) {
  __shared__ __align__(16) unsigned short As[128 * 32];
  __shared__ __align__(16) unsigned short Bs[128 * 32];

  const int nbn = N >> 7;
  const int nwg = (M >> 7) * nbn;
  int bid = blockIdx.x;
  bid = (bid & 7) * (nwg >> 3) + (bid >> 3);
  const int bm = bid / nbn;
  const int bn = bid - bm * nbn;

  const int tid  = threadIdx.x;
  const int lane = tid & 63;
  const int wv   = tid >> 6;
  const int wr   = wv >> 1;
  const int wc   = wv & 1;
  const int lrow = lane & 15;
  const int lk   = lane >> 4;

  const unsigned short* Abase = A  + (size_t)bm * 128 * lda;
  const unsigned short* Bbase = Bw + (size_t)bn * 128 * K;
  const int r0 = tid >> 2;
  const int c0 = (tid & 3) * 8;
  char* AsB = (char*)As + (size_t)wv * 1024;
  char* BsB = (char*)Bs + (size_t)wv * 1024;

  f32x4 acc[4][4];
#pragma unroll
  for (int m = 0; m < 4; m++)
#pragma unroll
    for (int n = 0; n < 4; n++) acc[m][n] = (f32x4){0.f, 0.f, 0.f, 0.f};

  for (int kt = 0; kt < K; kt += 32) {
    __syncthreads();
    gll16(Abase + (size_t)r0 * lda + kt + c0,        AsB);
    gll16(Abase + (size_t)(r0 + 64) * lda + kt + c0, AsB + 4096);
    gll16(Bbase + (size_t)r0 * K + kt + c0,          BsB);
    gll16(Bbase + (size_t)(r0 + 64) * K + kt + c0,   BsB + 4096);
    __syncthreads();

    const bf16x8* Av = (const bf16x8*)As;
    const bf16x8* Bv = (const bf16x8*)Bs;
    bf16x8 af[4], bfv[4];
#pragma unroll
    for (int m = 0; m < 4; m++) af[m]  = Av[(wr * 64 + m * 16 + lrow) * 4 + lk];
#pragma unroll
    for (int n = 0; n < 4; n++) bfv[n] = Bv[(wc * 64 + n * 16 + lrow) * 4 + lk];
#pragma unroll
    for (int m = 0; m < 4; m++)
#pragma unroll
      for (int n = 0; n < 4; n++)
        acc[m][n] = __builtin_amdgcn_mfma_f32_16x16x32_bf16(af[m], bfv[n], acc[m][n], 0, 0, 0);
  }

  const int rbase = bm * 128 + wr * 64 + (lane >> 4) * 4;
  const int cbase = bn * 128 + wc * 64 + (lane & 15);
#pragma unroll
  for (int n = 0; n < 4; n++) {
    const int col = cbase + n * 16;
    const float bi = bias0[col];
#pragma unroll
    for (int m = 0; m < 4; m++)
#pragma unroll
      for (int r = 0; r < 4; r++)
        out0[(size_t)(rbase + m * 16 + r) * ld0 + col] = acc[m][n][r] + bi;
  }
}

// ---------------- scan pass1 (per batch): A = prod c, B = local recurrence ---
__global__ __launch_bounds__(256) void k_scan1(const unsigned short* __restrict__ ghc,
                                               float* __restrict__ Ac,
                                               float* __restrict__ Bc) {
  int tid = threadIdx.x;
  int lane = tid & 63, cw = tid >> 6;
  int bid = blockIdx.x;
  int eg = bid & 63;
  int cq = bid >> 6;
  int chunk = cq * 4 + cw;
  int e = eg * 64 + lane;
  const unsigned short* cp = ghc + (size_t)(chunk * CLEN) * CN2E + e;
  float h = 0.f, A = 1.f;
#pragma unroll 8
  for (int t = 0; t < CLEN; t++) {
    float c  = bf2f(cp[(size_t)t * CN2E]);
    float gf = bf2f(cp[(size_t)t * CN2E + CE]);
    float v  = (1.f - c) * gf;
    h = __builtin_fmaf(c, h, v);
    A *= c;
  }
  Ac[(size_t)chunk * CE + e] = A;
  Bc[(size_t)chunk * CE + e] = h;
}

// ---------------- scan pass2 (per batch): combine -> exclusive h_start -------
__global__ __launch_bounds__(256) void k_scan2(const float* __restrict__ Ac,
                                               const float* __restrict__ Bc,
                                               float* __restrict__ Hs) {
  int e = blockIdx.x * 256 + threadIdx.x;
  float h = 0.f;
#pragma unroll
  for (int ch = 0; ch < NCHUNK; ch++) {
    Hs[(size_t)ch * CE + e] = h;
    h = __builtin_fmaf(Ac[(size_t)ch * CE + e], h, Bc[(size_t)ch * CE + e]);
  }
}

// ---------------- scan pass3 (per batch): recompute, s = x_skip + h (bf16) ----
__global__ __launch_bounds__(256) void k_scan3(const unsigned short* __restrict__ ghc,
                                               const float* __restrict__ Hs,
                                               const unsigned short* __restrict__ xs,
                                               unsigned short* __restrict__ sp) {
  int tid = threadIdx.x;
  int lane = tid & 63, cw = tid >> 6;
  int bid = blockIdx.x;
  int eg = bid & 63;
  int cq = bid >> 6;
  int chunk = cq * 4 + cw;
  int e = eg * 64 + lane;
  float h = Hs[(size_t)chunk * CE + e];
  const unsigned short* cp  = ghc + (size_t)(chunk * CLEN) * CN2E + e;
  const unsigned short* xsp = xs  + (size_t)(chunk * CLEN) * CE + e;
  unsigned short*       spp = sp  + (size_t)(chunk * CLEN) * CE + e;
#pragma unroll 4
  for (int t = 0; t < CLEN; t++) {
    float c  = bf2f(cp[(size_t)t * CN2E]);
    float gf = bf2f(cp[(size_t)t * CN2E + CE]);
    float v  = (1.f - c) * gf;
    h = __builtin_fmaf(c, h, v);
    float s = h + bf2f(xsp[(size_t)t * CE]);
    spp[(size_t)t * CE] = f2bf(s);
  }
}

// =======================================================================
extern "C" void kernel_launch(void* const* d_in, const int* in_sizes, int n_in,
                              void* d_out, int out_size, void* d_ws, size_t ws_size,
                              hipStream_t stream) {
  const float* x  = (const float*)d_in[0];
  const float* W1 = (const float*)d_in[1];
  const float* b1 = (const float*)d_in[2];
  const float* W2 = (const float*)d_in[3];
  const float* b2 = (const float*)d_in[4];
  const float* Wg = (const float*)d_in[5];
  const float* bg = (const float*)d_in[6];
  const float* Wo = (const float*)d_in[7];
  const float* bo = (const float*)d_in[8];
  float* out = (float*)d_out;

  const size_t MB = 1024 * 1024;
  if (ws_size < 234 * MB) return;   // clean fail instead of fault
  char* ws = (char*)d_ws;
  unsigned short* wgb   = (unsigned short*)(ws);             // 64 MB  Wg bf16 [2E][E]
  unsigned short* wob   = (unsigned short*)(ws + 64 * MB);   //  8 MB  Wo bf16 [D][E]
  unsigned short* wcat  = (unsigned short*)(ws + 72 * MB);   // 16 MB  [W1;W2] (dead after GEMM A)
  unsigned short* xb    = (unsigned short*)(ws + 88 * MB);   // 16 MB  x bf16  (dead after GEMM A)
  unsigned short* ghc   = (unsigned short*)(ws + 72 * MB);   // 32 MB  per-batch coeff|gf (alias)
  unsigned short* xin   = (unsigned short*)(ws + 104 * MB);  // 64 MB  x_in; becomes sbuf
  unsigned short* xskip = (unsigned short*)(ws + 168 * MB);  // 64 MB  x_skip
  float* Ac = (float*)(ws + 232 * MB);
  float* Bc = (float*)(ws + 232 * MB + 512 * 1024);
  float* Hs = (float*)(ws + 233 * MB);

  // allow 128 KB dynamic LDS on the 256^2 kernels (idempotent, non-stream)
  hipFuncSetAttribute(reinterpret_cast<const void*>(&gemm256<0>),
                      hipFuncAttributeMaxDynamicSharedMemorySize, 131072);
  hipFuncSetAttribute(reinterpret_cast<const void*>(&gemm256<2>),
                      hipFuncAttributeMaxDynamicSharedMemorySize, 131072);

  // ---- pack fp32 -> bf16 ----
  {
    int n4;
    n4 = CM * CD / 4;   k_f2bf4<<<n4 / 256, 256, 0, stream>>>(x,  xb,   n4);
    n4 = CE * CD / 4;   k_f2bf4<<<n4 / 256, 256, 0, stream>>>(W1, wcat, n4);
    n4 = CE * CD / 4;   k_f2bf4<<<n4 / 256, 256, 0, stream>>>(W2, wcat + (size_t)CE * CD, n4);
    n4 = CN2E * CE / 4; k_f2bf4<<<n4 / 256, 256, 0, stream>>>(Wg, wgb,  n4);
    n4 = CD * CE / 4;   k_f2bf4<<<n4 / 256, 256, 0, stream>>>(Wo, wob,  n4);
  }

  // ---- GEMM A: [x_in|x_skip] = silu(xb @ wcat^T + [b1|b2]); 8192x8192x1024 ----
  gemm256<0><<<(CM / 256) * (CN2E / 256), 512, 131072, stream>>>(
      xb, wcat, b1, b2, xin, xskip, CM, CN2E, CD, CD, CE, CE);

  // ---- per batch: gate GEMM (2048x8192x4096, +transform epilogue) then scan ----
  for (int b = 0; b < CB; b++) {
    const unsigned short* xin_b = xin + (size_t)b * CT * CE;
    gemm256<2><<<(CT / 256) * (CN2E / 256), 512, 131072, stream>>>(
        xin_b, wgb, bg, nullptr, ghc, nullptr, CT, CN2E, CE, CE, CN2E, CE);
    k_scan1<<<512, 256, 0, stream>>>(ghc, Ac, Bc);
    k_scan2<<<CE / 256, 256, 0, stream>>>(Ac, Bc, Hs);
    k_scan3<<<512, 256, 0, stream>>>(ghc, Hs, xskip + (size_t)b * CT * CE,
                                     xin + (size_t)b * CT * CE);
  }

  // ---- GEMM C: out = sbuf @ Wo^T + bo; 8192x1024x4096 (128^2 kernel) ----
  gemm_bt1<<<(CM / 128) * (CD / 128), 256, 0, stream>>>(
      xin, wob, bo, out, CM, CD, CE, CE, CD);
}

// Round 4
// 928.655 us; speedup vs baseline: 1.5337x; 1.0541x over previous
//
#include <hip/hip_runtime.h>
#include <cstdint>
#include <cstddef>

// Problem constants
constexpr int CB  = 4;
constexpr int CT  = 2048;
constexpr int CD  = 1024;
constexpr int CE  = 4096;
constexpr int CM  = CB * CT;      // 8192 token rows
constexpr int CN2E = 2 * CE;      // 8192
constexpr int NCHUNK = 32;        // per-batch T chunks for scan
constexpr int CLEN = CT / NCHUNK; // 64

typedef float  f32x4  __attribute__((ext_vector_type(4)));
typedef __bf16 bf16x8 __attribute__((ext_vector_type(8)));

__device__ __forceinline__ unsigned short f2bf(float f) {
  unsigned int u = __float_as_uint(f);
  unsigned int r = u + 0x7FFFu + ((u >> 16) & 1u);   // RNE
  return (unsigned short)(r >> 16);
}
__device__ __forceinline__ float bf2f(unsigned short h) {
  return __uint_as_float(((unsigned int)h) << 16);
}

// ---------------- fp32 -> bf16 pack (vectorized x4) ----------------
__global__ __launch_bounds__(256) void k_f2bf4(const float* __restrict__ in,
                                               unsigned short* __restrict__ out, int n4) {
  int i = blockIdx.x * 256 + threadIdx.x;
  if (i >= n4) return;
  float4 v = ((const float4*)in)[i];
  ushort4 o;
  o.x = f2bf(v.x); o.y = f2bf(v.y); o.z = f2bf(v.z); o.w = f2bf(v.w);
  ((ushort4*)out)[i] = o;
}

// ---------------- async global->LDS, 16B per lane ----------------
__device__ __forceinline__ void gll16(const unsigned short* g, void* l) {
  __builtin_amdgcn_global_load_lds(
      (const __attribute__((address_space(1))) void*)g,
      (__attribute__((address_space(3))) void*)l, 16, 0, 0);
}

// =====================================================================
// 256x256 tile, BK=64, 8 waves (2M x 4N), 2-deep LDS double buffer,
// 4 phases/tile {ds_read || stage ; barrier ; setprio MFMA16}, counted
// staging drained once per tile. LDS: 2 bufs x (A 32KB | B 32KB) = 128KB.
// Swizzle: stage source chunk ^= row&7 (LDS dest linear), read chunk
// (ks*4+lk)^(lr&7) -> conflict-free ds_read_b128.
// EPI 0: bias(b0|b1 @esplit) + silu -> bf16 out0|out1 (ld0 each)
// EPI 2: bias0; col<esplit -> sigmoid(-v) else g(v) -> bf16 out0
template <int EPI>
__global__ __launch_bounds__(512, 2) void gemm256(
    const unsigned short* __restrict__ A,   // [M][lda] bf16
    const unsigned short* __restrict__ Bw,  // [N][K]   bf16 (tight)
    const float* __restrict__ bias0,
    const float* __restrict__ bias1,
    void* __restrict__ out0,
    void* __restrict__ out1,
    int M, int N, int K, int lda, int ld0, int esplit) {
  extern __shared__ char lds[];   // 131072 bytes

  const int nbn = N >> 8;
  const int nbm = M >> 8;
  const int nwg = nbm * nbn;
  int bid = blockIdx.x;
  int tau = (bid & 7) * (nwg >> 3) + (bid >> 3);   // XCD chunking (nwg%8==0)
  const int gsz = nbm * 4;                          // group = 4 bn-cols x all bm
  int gg  = tau / gsz;
  int rem = tau - gg * gsz;
  const int bm = rem >> 2;
  const int bn = gg * 4 + (rem & 3);

  const int tid  = threadIdx.x;
  const int lane = tid & 63;
  const int wv   = tid >> 6;
  const int wr   = wv >> 2;       // 0..1
  const int wc   = wv & 3;        // 0..3

  // ---- staging map (G-load = 512 thr x 16B = 64 rows x 64 k-elems) ----
  // thread covers LDS slot (row = g*64 + tid>>3, phys chunk = tid&7);
  // source chunk pre-swizzled so phys = logical ^ (row&7).
  const int sr  = tid >> 3;                       // 0..63 row within G-load
  const int sc8 = (((tid & 7) ^ (sr & 7)) * 8);   // k-element offset (swz src)

  const unsigned short* Abase = A  + (size_t)bm * 256 * lda;
  const unsigned short* Bbase = Bw + (size_t)bn * 256 * (size_t)K;
  const int NT = K >> 6;

  auto stageA = [&](int t) {
    char* base = lds + (size_t)(t & 1) * 65536 + wv * 1024;
    const unsigned short* g = Abase + t * 64 + sc8;
#pragma unroll
    for (int q = 0; q < 4; q++)
      gll16(g + (size_t)(q * 64 + sr) * lda, base + q * 8192);
  };
  auto stageB = [&](int t) {
    char* base = lds + (size_t)(t & 1) * 65536 + 32768 + wv * 1024;
    const unsigned short* g = Bbase + t * 64 + sc8;
#pragma unroll
    for (int q = 0; q < 4; q++)
      gll16(g + (size_t)(q * 64 + sr) * K, base + q * 8192);
  };

  // ---- fragment read offsets ----
  const int lr = lane & 15, lk = lane >> 4;
  const int pk[2] = { ((lk)     ^ (lr & 7)) * 16,     // ks=0
                      ((4 + lk) ^ (lr & 7)) * 16 };   // ks=1
  const int aLaneB = (wr * 128 + lr) * 128;
  const int bLaneB = 32768 + (wc * 64 + lr) * 128;

  f32x4 acc[8][4];
#pragma unroll
  for (int m = 0; m < 8; m++)
#pragma unroll
    for (int n = 0; n < 4; n++) acc[m][n] = (f32x4){0.f, 0.f, 0.f, 0.f};

  // ---- prologue: stage tile 0, drain, barrier ----
  stageA(0); stageB(0);
  asm volatile("s_waitcnt vmcnt(0)" ::: "memory");
  __builtin_amdgcn_sched_barrier(0);
  __builtin_amdgcn_s_barrier();
  __builtin_amdgcn_sched_barrier(0);

  for (int t = 0; t < NT; t++) {
    const char* bp = lds + (size_t)(t & 1) * 65536;
    bf16x8 bfr[2][4];   // [ks][nf], read once per tile (phase 0)

#pragma unroll
    for (int p = 0; p < 4; p++) {
      // ---- reads for this phase (quadrant mf = 2p, 2p+1) ----
      bf16x8 aq[2][2];  // [q][ks]
#pragma unroll
      for (int q = 0; q < 2; q++)
#pragma unroll
        for (int ks = 0; ks < 2; ks++)
          aq[q][ks] = *(const bf16x8*)(bp + aLaneB + (2 * p + q) * 2048 + pk[ks]);
      if (p == 0) {
#pragma unroll
        for (int ks = 0; ks < 2; ks++)
#pragma unroll
          for (int nf = 0; nf < 4; nf++)
            bfr[ks][nf] = *(const bf16x8*)(bp + bLaneB + nf * 2048 + pk[ks]);
        if (t + 1 < NT) stageA(t + 1);
      }
      if (p == 1 && t + 1 < NT) stageB(t + 1);
      __builtin_amdgcn_s_barrier();
      __builtin_amdgcn_s_setprio(1);
#pragma unroll
      for (int ks = 0; ks < 2; ks++)
#pragma unroll
        for (int q = 0; q < 2; q++)
#pragma unroll
          for (int nf = 0; nf < 4; nf++)
            acc[2 * p + q][nf] = __builtin_amdgcn_mfma_f32_16x16x32_bf16(
                aq[q][ks], bfr[ks][nf], acc[2 * p + q][nf], 0, 0, 0);
      __builtin_amdgcn_s_setprio(0);
    }

    // ---- tile boundary: next tile's data (staged phases 0-1) must land ----
    asm volatile("s_waitcnt vmcnt(0)" ::: "memory");
    __builtin_amdgcn_sched_barrier(0);
    __builtin_amdgcn_s_barrier();
    __builtin_amdgcn_sched_barrier(0);
  }

  // ---- epilogue: C/D layout col=lane&15, row=(lane>>4)*4+reg ----
  const int rb = bm * 256 + wr * 128 + (lane >> 4) * 4;
  const int cb = bn * 256 + wc * 64 + (lane & 15);
#pragma unroll
  for (int nf = 0; nf < 4; nf++) {
    const int col = cb + nf * 16;
    float bi;
    if (EPI == 0) bi = (col < esplit) ? bias0[col] : bias1[col - esplit];
    else          bi = bias0[col];
#pragma unroll
    for (int mf = 0; mf < 8; mf++) {
#pragma unroll
      for (int r = 0; r < 4; r++) {
        const int row = rb + mf * 16 + r;
        float v = acc[mf][nf][r] + bi;
        if (EPI == 0) {
          float sg = 1.f / (1.f + __expf(-v));
          unsigned short o = f2bf(v * sg);
          if (col < esplit) ((unsigned short*)out0)[(size_t)row * ld0 + col] = o;
          else              ((unsigned short*)out1)[(size_t)row * ld0 + (col - esplit)] = o;
        } else {  // EPI == 2: gate transform
          unsigned short o;
          if (col < esplit) {
            float e = __expf(-fabsf(v));
            float inv = 1.f / (1.f + e);
            o = f2bf((v >= 0.f) ? e * inv : inv);     // sigmoid(-v)
          } else {
            float gf;
            if (v >= 0.f) gf = v + 0.5f;
            else { float eh = __expf(v); gf = eh / (1.f + eh); }
            o = f2bf(gf);                              // g(v)
          }
          ((unsigned short*)out0)[(size_t)row * ld0 + col] = o;
        }
      }
    }
  }
}

// ---------------- 128^2 m97-structure GEMM (kept for GEMM C) ----------------
__global__ __launch_bounds__(256) void gemm_bt1(
    const unsigned short* __restrict__ A,   // [M][lda] bf16
    const unsigned short* __restrict__ Bw,  // [N][K]   bf16 (tight)
    const float* __restrict__ bias0,
    float* __restrict__ out0,
    int M, int N, int K, int lda, int ld0) {
  __shared__ __align__(16) unsigned short As[128 * 32];
  __shared__ __align__(16) unsigned short Bs[128 * 32];

  const int nbn = N >> 7;
  const int nwg = (M >> 7) * nbn;
  int bid = blockIdx.x;
  bid = (bid & 7) * (nwg >> 3) + (bid >> 3);
  const int bm = bid / nbn;
  const int bn = bid - bm * nbn;

  const int tid  = threadIdx.x;
  const int lane = tid & 63;
  const int wv   = tid >> 6;
  const int wr   = wv >> 1;
  const int wc   = wv & 1;
  const int lrow = lane & 15;
  const int lk   = lane >> 4;

  const unsigned short* Abase = A  + (size_t)bm * 128 * lda;
  const unsigned short* Bbase = Bw + (size_t)bn * 128 * K;
  const int r0 = tid >> 2;
  const int c0 = (tid & 3) * 8;
  char* AsB = (char*)As + (size_t)wv * 1024;
  char* BsB = (char*)Bs + (size_t)wv * 1024;

  f32x4 acc[4][4];
#pragma unroll
  for (int m = 0; m < 4; m++)
#pragma unroll
    for (int n = 0; n < 4; n++) acc[m][n] = (f32x4){0.f, 0.f, 0.f, 0.f};

  for (int kt = 0; kt < K; kt += 32) {
    __syncthreads();
    gll16(Abase + (size_t)r0 * lda + kt + c0,        AsB);
    gll16(Abase + (size_t)(r0 + 64) * lda + kt + c0, AsB + 4096);
    gll16(Bbase + (size_t)r0 * K + kt + c0,          BsB);
    gll16(Bbase + (size_t)(r0 + 64) * K + kt + c0,   BsB + 4096);
    __syncthreads();

    const bf16x8* Av = (const bf16x8*)As;
    const bf16x8* Bv = (const bf16x8*)Bs;
    bf16x8 af[4], bfv[4];
#pragma unroll
    for (int m = 0; m < 4; m++) af[m]  = Av[(wr * 64 + m * 16 + lrow) * 4 + lk];
#pragma unroll
    for (int n = 0; n < 4; n++) bfv[n] = Bv[(wc * 64 + n * 16 + lrow) * 4 + lk];
#pragma unroll
    for (int m = 0; m < 4; m++)
#pragma unroll
      for (int n = 0; n < 4; n++)
        acc[m][n] = __builtin_amdgcn_mfma_f32_16x16x32_bf16(af[m], bfv[n], acc[m][n], 0, 0, 0);
  }

  const int rbase = bm * 128 + wr * 64 + (lane >> 4) * 4;
  const int cbase = bn * 128 + wc * 64 + (lane & 15);
#pragma unroll
  for (int n = 0; n < 4; n++) {
    const int col = cbase + n * 16;
    const float bi = bias0[col];
#pragma unroll
    for (int m = 0; m < 4; m++)
#pragma unroll
      for (int r = 0; r < 4; r++)
        out0[(size_t)(rbase + m * 16 + r) * ld0 + col] = acc[m][n][r] + bi;
  }
}

// ---------------- scan pass1 (per batch): A = prod c, B = local recurrence ---
__global__ __launch_bounds__(256) void k_scan1(const unsigned short* __restrict__ ghc,
                                               float* __restrict__ Ac,
                                               float* __restrict__ Bc) {
  int tid = threadIdx.x;
  int lane = tid & 63, cw = tid >> 6;
  int bid = blockIdx.x;
  int eg = bid & 63;
  int cq = bid >> 6;
  int chunk = cq * 4 + cw;
  int e = eg * 64 + lane;
  const unsigned short* cp = ghc + (size_t)(chunk * CLEN) * CN2E + e;
  float h = 0.f, A = 1.f;
#pragma unroll 8
  for (int t = 0; t < CLEN; t++) {
    float c  = bf2f(cp[(size_t)t * CN2E]);
    float gf = bf2f(cp[(size_t)t * CN2E + CE]);
    float v  = (1.f - c) * gf;
    h = __builtin_fmaf(c, h, v);
    A *= c;
  }
  Ac[(size_t)chunk * CE + e] = A;
  Bc[(size_t)chunk * CE + e] = h;
}

// ---------------- scan pass2 (per batch): combine -> exclusive h_start -------
__global__ __launch_bounds__(256) void k_scan2(const float* __restrict__ Ac,
                                               const float* __restrict__ Bc,
                                               float* __restrict__ Hs) {
  int e = blockIdx.x * 256 + threadIdx.x;
  float h = 0.f;
#pragma unroll
  for (int ch = 0; ch < NCHUNK; ch++) {
    Hs[(size_t)ch * CE + e] = h;
    h = __builtin_fmaf(Ac[(size_t)ch * CE + e], h, Bc[(size_t)ch * CE + e]);
  }
}

// ---------------- scan pass3 (per batch): recompute, s = x_skip + h (bf16) ----
__global__ __launch_bounds__(256) void k_scan3(const unsigned short* __restrict__ ghc,
                                               const float* __restrict__ Hs,
                                               const unsigned short* __restrict__ xs,
                                               unsigned short* __restrict__ sp) {
  int tid = threadIdx.x;
  int lane = tid & 63, cw = tid >> 6;
  int bid = blockIdx.x;
  int eg = bid & 63;
  int cq = bid >> 6;
  int chunk = cq * 4 + cw;
  int e = eg * 64 + lane;
  float h = Hs[(size_t)chunk * CE + e];
  const unsigned short* cp  = ghc + (size_t)(chunk * CLEN) * CN2E + e;
  const unsigned short* xsp = xs  + (size_t)(chunk * CLEN) * CE + e;
  unsigned short*       spp = sp  + (size_t)(chunk * CLEN) * CE + e;
#pragma unroll 4
  for (int t = 0; t < CLEN; t++) {
    float c  = bf2f(cp[(size_t)t * CN2E]);
    float gf = bf2f(cp[(size_t)t * CN2E + CE]);
    float v  = (1.f - c) * gf;
    h = __builtin_fmaf(c, h, v);
    float s = h + bf2f(xsp[(size_t)t * CE]);
    spp[(size_t)t * CE] = f2bf(s);
  }
}

// =======================================================================
extern "C" void kernel_launch(void* const* d_in, const int* in_sizes, int n_in,
                              void* d_out, int out_size, void* d_ws, size_t ws_size,
                              hipStream_t stream) {
  const float* x  = (const float*)d_in[0];
  const float* W1 = (const float*)d_in[1];
  const float* b1 = (const float*)d_in[2];
  const float* W2 = (const float*)d_in[3];
  const float* b2 = (const float*)d_in[4];
  const float* Wg = (const float*)d_in[5];
  const float* bg = (const float*)d_in[6];
  const float* Wo = (const float*)d_in[7];
  const float* bo = (const float*)d_in[8];
  float* out = (float*)d_out;

  const size_t MB = 1024 * 1024;
  if (ws_size < 234 * MB) return;   // clean fail instead of fault
  char* ws = (char*)d_ws;
  unsigned short* wgb   = (unsigned short*)(ws);             // 64 MB  Wg bf16 [2E][E]
  unsigned short* wob   = (unsigned short*)(ws + 64 * MB);   //  8 MB  Wo bf16 [D][E]
  unsigned short* wcat  = (unsigned short*)(ws + 72 * MB);   // 16 MB  [W1;W2] (dead after GEMM A)
  unsigned short* xb    = (unsigned short*)(ws + 88 * MB);   // 16 MB  x bf16  (dead after GEMM A)
  unsigned short* ghc   = (unsigned short*)(ws + 72 * MB);   // 32 MB  per-batch coeff|gf (alias)
  unsigned short* xin   = (unsigned short*)(ws + 104 * MB);  // 64 MB  x_in; becomes sbuf
  unsigned short* xskip = (unsigned short*)(ws + 168 * MB);  // 64 MB  x_skip
  float* Ac = (float*)(ws + 232 * MB);
  float* Bc = (float*)(ws + 232 * MB + 512 * 1024);
  float* Hs = (float*)(ws + 233 * MB);

  // allow 128 KB dynamic LDS on the 256^2 kernels (idempotent, non-stream)
  hipFuncSetAttribute(reinterpret_cast<const void*>(&gemm256<0>),
                      hipFuncAttributeMaxDynamicSharedMemorySize, 131072);
  hipFuncSetAttribute(reinterpret_cast<const void*>(&gemm256<2>),
                      hipFuncAttributeMaxDynamicSharedMemorySize, 131072);

  // ---- pack fp32 -> bf16 ----
  {
    int n4;
    n4 = CM * CD / 4;   k_f2bf4<<<n4 / 256, 256, 0, stream>>>(x,  xb,   n4);
    n4 = CE * CD / 4;   k_f2bf4<<<n4 / 256, 256, 0, stream>>>(W1, wcat, n4);
    n4 = CE * CD / 4;   k_f2bf4<<<n4 / 256, 256, 0, stream>>>(W2, wcat + (size_t)CE * CD, n4);
    n4 = CN2E * CE / 4; k_f2bf4<<<n4 / 256, 256, 0, stream>>>(Wg, wgb,  n4);
    n4 = CD * CE / 4;   k_f2bf4<<<n4 / 256, 256, 0, stream>>>(Wo, wob,  n4);
  }

  // ---- GEMM A: [x_in|x_skip] = silu(xb @ wcat^T + [b1|b2]); 8192x8192x1024 ----
  gemm256<0><<<(CM / 256) * (CN2E / 256), 512, 131072, stream>>>(
      xb, wcat, b1, b2, xin, xskip, CM, CN2E, CD, CD, CE, CE);

  // ---- per batch: gate GEMM (2048x8192x4096, +transform epilogue) then scan ----
  for (int b = 0; b < CB; b++) {
    const unsigned short* xin_b = xin + (size_t)b * CT * CE;
    gemm256<2><<<(CT / 256) * (CN2E / 256), 512, 131072, stream>>>(
        xin_b, wgb, bg, nullptr, ghc, nullptr, CT, CN2E, CE, CE, CN2E, CE);
    k_scan1<<<512, 256, 0, stream>>>(ghc, Ac, Bc);
    k_scan2<<<CE / 256, 256, 0, stream>>>(Ac, Bc, Hs);
    k_scan3<<<512, 256, 0, stream>>>(ghc, Hs, xskip + (size_t)b * CT * CE,
                                     xin + (size_t)b * CT * CE);
  }

  // ---- GEMM C: out = sbuf @ Wo^T + bo; 8192x1024x4096 (128^2 kernel) ----
  gemm_bt1<<<(CM / 128) * (CD / 128), 256, 0, stream>>>(
      xin, wob, bo, out, CM, CD, CE, CE, CD);
}